// Round 5
// baseline (545.010 us; speedup 1.0000x reference)
//
#include <hip/hip_runtime.h>

typedef unsigned short u16;
typedef unsigned int u32;
typedef __bf16 bf16x8 __attribute__((ext_vector_type(8)));
typedef float f32x16 __attribute__((ext_vector_type(16)));

// Problem constants: B=4, N=2048, C=2048, H=16, DH=128
// tokens BN = 8192, qkv row = 3*C = 6144

__device__ __forceinline__ u16 f2bf(float f) {
    u32 u = __builtin_bit_cast(u32, f);
    u += 0x7FFFu + ((u >> 16) & 1u);   // round-to-nearest-even
    return (u16)(u >> 16);
}
__device__ __forceinline__ float bf2f(u16 h) {
    return __builtin_bit_cast(float, ((u32)h) << 16);
}

// ---------------- fp32 -> bf16 conversion (vectorized) ----------------
__global__ __launch_bounds__(256) void cvt_bf16(const float* __restrict__ in,
                                                u16* __restrict__ out, int n4) {
    int i = blockIdx.x * 256 + threadIdx.x;
    if (i >= n4) return;
    const float4 f = reinterpret_cast<const float4*>(in)[i];
    ushort4 o;
    o.x = f2bf(f.x); o.y = f2bf(f.y); o.z = f2bf(f.z); o.w = f2bf(f.w);
    reinterpret_cast<ushort4*>(out)[i] = o;
}

// ---------------- async global->LDS copy, 16 B per lane ----------------
typedef const __attribute__((address_space(1))) void* gas1_t;
typedef __attribute__((address_space(3))) void* las3_t;
__device__ __forceinline__ void cp16(const void* g, void* l) {
    __builtin_amdgcn_global_load_lds((gas1_t)g, (las3_t)l, 16, 0, 0);
}

#define BAR()        __builtin_amdgcn_s_barrier()
#define SBAR0()      __builtin_amdgcn_sched_barrier(0)
#define WAIT_VM(n)   asm volatile("s_waitcnt vmcnt(" #n ")" ::: "memory")

// ==================== 128x256 ring-3 bf16 NT GEMM ====================
// C = A(MxK) * B(NxK)^T + bias.  BM=128, BN=256, BK=32, 512 threads = 8 waves
// (2M x 4N), per-wave output 64x64 = 2x2 of 32x32x16 MFMA, acc = 4 x f32x16.
//
// Design (from round-4 counters: Occupancy 21.6% = 1 block/CU at 128 KiB LDS;
// 8 barriers/K-tile were unhidden convoys):
//  - LDS ring-3 x 24 KiB = 72 KiB  ->  2 blocks/CU co-resident. Cross-block
//    overlap hides the single per-K-tile barrier.
//  - ONE phase / ONE barrier per K-tile: stage T+2 (3 cp16/thread) ->
//    8 ds_read_b128 -> 8 MFMA -> vmcnt(3) -> s_barrier.
//    vm ledger (3 cp16/tile): prologue stages T0,T1 (6 out), vm(3) drains T0.
//    iter T: stage T+2 (6 out); vm(3) drains T+1; never 0 in the loop.
//    Race-freedom: stage T+2 writes buf[(T+2)%3] = buf[(T-1)%3], whose last
//    reads finished before the previous barrier (reads are consumed by MFMA
//    before the barrier; compiler inserts the counted lgkm waits).
//  - Layout per buf (24 KiB): A 128x32 @0 (8 KiB), B 256x32 @8192 (16 KiB).
//    Line-local granule map (round-4 proven coalesced):
//    granule(r, kc 0..3) at byte r*64 + ((kc + r)&3)*16.  gload_lds dest is
//    linear tid*16; permutation lives in the per-lane GLOBAL source: 4-thread
//    row-runs cover each row's full 64 B -> whole cache lines.
//  - Bijective XCD swizzle (nwg%8==0 for both grids): each XCD gets a
//    contiguous run of flat ids -> consecutive blocks share the A-panel in
//    that XCD's L2 (round-4 ran unswizzled at 3x-ideal FETCH).

template <int OUT_BF16>
__global__ __launch_bounds__(512, 4) void gemm_nt(const u16* __restrict__ A,
                                                  const u16* __restrict__ Bm,
                                                  const float* __restrict__ bias,
                                                  void* __restrict__ Cout,
                                                  int M, int N, int K) {
    __shared__ __align__(16) char lds[3 * 24576];

    const int tid  = threadIdx.x;
    const int lane = tid & 63;
    const int wave = tid >> 6;
    const int wm   = (wave >> 2) * 64;  // 0 or 64 (M half)
    const int wn   = (wave & 3) * 64;   // 0..192  (N quarter)
    const int r32  = lane & 31;
    const int half = lane >> 5;         // 0..1

    // bijective XCD swizzle on the flat block id (nwg % 8 == 0 at our grids)
    const int gx   = gridDim.x;
    const int flat = blockIdx.y * gx + blockIdx.x;
    const int q8   = (gx * gridDim.y) >> 3;
    const int swz  = (flat & 7) * q8 + (flat >> 3);
    const long bm  = (long)(swz / gx) * 128;
    const long bn  = (long)(swz % gx) * 256;

    // ---- staging sources (line-local): thread t -> granule (row=t>>2,
    // slot-in-row = t&3 which holds kc = ((t&3) - row)&3); dest = tid*16 ----
    const int sr = tid >> 2;                 // 0..127
    const int sk = ((tid & 3) - sr) & 3;     // source k-chunk for this slot
    const u16* sA  = A  + (bm + sr) * (long)K + sk * 8;
    const u16* sB0 = Bm + (bn + sr) * (long)K + sk * 8;
    const u16* sB1 = sB0 + 128 * (long)K;
    char* ld0 = lds + tid * 16;

#define STAGE(BO, KT)                                               \
    { const long ko = (long)(KT) * 32;                              \
      char* d = ld0 + (BO);                                         \
      cp16(sA  + ko, d);                                            \
      cp16(sB0 + ko, d + 8192);                                     \
      cp16(sB1 + ko, d + 16384); }

    // ---- frag read bases: addr = bufo + [A: (wm+mt*32+r32)*64 | B: 8192 +
    // (wn+nt*32+r32)*64] + ((kc + r32)&3)*16, kc = 2*ks + half ----
    const char* pA = lds + (wm + r32) * 64;
    const char* pB = lds + 8192 + (wn + r32) * 64;
    int o2[2];
#pragma unroll
    for (int ks = 0; ks < 2; ++ks) o2[ks] = (((2 * ks + half) + r32) & 3) * 16;

    f32x16 acc[2][2];
#pragma unroll
    for (int i = 0; i < 2; ++i)
#pragma unroll
        for (int j = 0; j < 2; ++j)
#pragma unroll
            for (int r = 0; r < 16; ++r) acc[i][j][r] = 0.f;

    const int NT = K >> 5;      // 64 K-tiles at K=2048

    // ---- prologue: stage tiles 0,1 into bufs 0,1; drain tile 0 only ----
    STAGE(0, 0); STAGE(24576, 1);
    WAIT_VM(3);
    BAR(); SBAR0();

    int bro = 0;          // byte offset of read buffer  (t   % 3)
    int bso = 49152;      // byte offset of stage buffer (t+2 % 3)
    for (int t = 0; t < NT; ++t) {
        int kt = t + 2; if (kt >= NT) kt -= NT;   // tail wrap: harmless refetch
        STAGE(bso, kt);

        bf16x8 a[2][2], b[2][2];
#pragma unroll
        for (int ks = 0; ks < 2; ++ks)
#pragma unroll
            for (int u = 0; u < 2; ++u) {
                a[u][ks] = *(const bf16x8*)(pA + bro + u * 2048 + o2[ks]);
                b[u][ks] = *(const bf16x8*)(pB + bro + u * 2048 + o2[ks]);
            }

        __builtin_amdgcn_s_setprio(1);
#pragma unroll
        for (int ks = 0; ks < 2; ++ks)
#pragma unroll
            for (int i = 0; i < 2; ++i)
#pragma unroll
                for (int j = 0; j < 2; ++j)
                    acc[i][j] = __builtin_amdgcn_mfma_f32_32x32x16_bf16(
                        a[i][ks], b[j][ks], acc[i][j], 0, 0, 0);
        __builtin_amdgcn_s_setprio(0);

        // counted drain: tile t+1 (issued last iteration) complete; leave
        // t+2's 3 loads in flight.  Single barrier releases buf (t-1)%3.
        WAIT_VM(3);
        BAR(); SBAR0();

        bro += 24576; if (bro == 73728) bro = 0;
        bso += 24576; if (bso == 73728) bso = 0;
    }
#undef STAGE

    WAIT_VM(0);   // drain wasted tail prefetches before epilogue vmem

    // ---- epilogue: 32x32 C/D layout col=lane&31, row=(reg&3)+8*(reg>>2)+4*half
    // stores: 32 cols x 2 B = full 64 B lines ----
#pragma unroll
    for (int j = 0; j < 2; ++j) {
        const long col = bn + wn + j * 32 + r32;
        const float bc = bias[col];
#pragma unroll
        for (int i = 0; i < 2; ++i) {
#pragma unroll
            for (int reg = 0; reg < 16; ++reg) {
                const long row = bm + wm + i * 32 + (reg & 3) + 8 * (reg >> 2) + 4 * half;
                float v = acc[i][j][reg] + bc;
                if (OUT_BF16)
                    ((u16*)Cout)[row * (long)N + col] = f2bf(v);
                else
                    ((float*)Cout)[row * (long)N + col] = v;
            }
        }
    }
}

// ---------------- per-token head-mixing attention ----------------
// One block (256 thr) per token. q,k,v: 16x128 each from qkv row (3*2048 bf16).
// S = q k^T / sqrt(2048) (16x16), softmax rows, O = S v (16x128).
// Write O to scrambled layout: row h*128 + n/16, col (n%16)*128 + d (bf16).
__global__ __launch_bounds__(256) void attn(const u16* __restrict__ qkv,
                                            u16* __restrict__ outb) {
    __shared__ float sQ[16 * 132];   // +4 pad: stride 132 floats kills bank conflicts
    __shared__ float sK[16 * 132];
    __shared__ float sV[16 * 132];
    __shared__ float sP[16 * 17];

    const int tid = threadIdx.x;
    const int token = blockIdx.x;
    const int b = token >> 11;      // /2048
    const int n = token & 2047;
    const u16* row = qkv + (long)token * 6144;

    // ---- load q,k,v -> LDS as fp32 (each thread: 8 contiguous elems) ----
    {
        const int r  = tid >> 4;          // 0..15
        const int c8 = (tid & 15) * 8;    // 0,8,...,120
#pragma unroll
        for (int m = 0; m < 3; ++m) {
            const uint4 u = *reinterpret_cast<const uint4*>(row + m * 2048 + tid * 8);
            float* dst = (m == 0 ? sQ : (m == 1 ? sK : sV)) + r * 132 + c8;
            float4 lo, hi;
            lo.x = bf2f((u16)u.x); lo.y = bf2f((u16)(u.x >> 16));
            lo.z = bf2f((u16)u.y); lo.w = bf2f((u16)(u.y >> 16));
            hi.x = bf2f((u16)u.z); hi.y = bf2f((u16)(u.z >> 16));
            hi.z = bf2f((u16)u.w); hi.w = bf2f((u16)(u.w >> 16));
            *reinterpret_cast<float4*>(dst)     = lo;
            *reinterpret_cast<float4*>(dst + 4) = hi;
        }
    }
    __syncthreads();

    // ---- S + softmax: thread (h,g) = (tid>>4, tid&15); 16-lane-group reductions ----
    {
        const int h = tid >> 4, g = tid & 15;
        const float4* qr = reinterpret_cast<const float4*>(&sQ[h * 132]);
        const float4* kr = reinterpret_cast<const float4*>(&sK[g * 132]);
        float s = 0.f;
#pragma unroll
        for (int d = 0; d < 32; ++d) {
            const float4 a = qr[d], k4 = kr[d];
            s += a.x * k4.x + a.y * k4.y + a.z * k4.z + a.w * k4.w;
        }
        s *= 0.022097086912079608f;   // 1/sqrt(2048)
        float mx = s;
#pragma unroll
        for (int o = 8; o >= 1; o >>= 1) mx = fmaxf(mx, __shfl_xor(mx, o, 16));
        const float e = __expf(s - mx);
        float sum = e;
#pragma unroll
        for (int o = 8; o >= 1; o >>= 1) sum += __shfl_xor(sum, o, 16);
        sP[h * 17 + g] = e / sum;
    }
    __syncthreads();

    // ---- O = P @ V; thread (h, dblk) handles d = dblk*8 .. +7 ----
    {
        const int h = tid >> 4, dblk = tid & 15;
        float p[16];
#pragma unroll
        for (int g = 0; g < 16; ++g) p[g] = sP[h * 17 + g];
        float4 o0 = {0.f, 0.f, 0.f, 0.f}, o1 = {0.f, 0.f, 0.f, 0.f};
#pragma unroll
        for (int g = 0; g < 16; ++g) {
            const float* vr = &sV[g * 132 + dblk * 8];
            const float4 v0 = *reinterpret_cast<const float4*>(vr);
            const float4 v1 = *reinterpret_cast<const float4*>(vr + 4);
            o0.x += p[g] * v0.x; o0.y += p[g] * v0.y; o0.z += p[g] * v0.z; o0.w += p[g] * v0.w;
            o1.x += p[g] * v1.x; o1.y += p[g] * v1.y; o1.z += p[g] * v1.z; o1.w += p[g] * v1.w;
        }
        // scrambled reshape target: row = h*128 + n/16, col = (n%16)*128 + d
        const long rr = (long)h * 128 + (n >> 4);
        const long cc = (long)(n & 15) * 128 + dblk * 8;
        u16* dst = outb + ((long)b * 2048 + rr) * 2048 + cc;
        uint4 pk;
        pk.x = (u32)f2bf(o0.x) | ((u32)f2bf(o0.y) << 16);
        pk.y = (u32)f2bf(o0.z) | ((u32)f2bf(o0.w) << 16);
        pk.z = (u32)f2bf(o1.x) | ((u32)f2bf(o1.y) << 16);
        pk.w = (u32)f2bf(o1.z) | ((u32)f2bf(o1.w) << 16);
        *reinterpret_cast<uint4*>(dst) = pk;
    }
}

// ---------------- launch ----------------
extern "C" void kernel_launch(void* const* d_in, const int* in_sizes, int n_in,
                              void* d_out, int out_size, void* d_ws, size_t ws_size,
                              hipStream_t stream) {
    const float* x     = (const float*)d_in[0];   // (4,2048,2048)
    const float* w_qkv = (const float*)d_in[1];   // (6144,2048)
    const float* b_qkv = (const float*)d_in[2];   // (6144,)
    const float* w_out = (const float*)d_in[3];   // (2048,2048)
    const float* b_out = (const float*)d_in[4];   // (2048,)
    float* out = (float*)d_out;                   // (4,2048,2048) fp32

    char* ws = (char*)d_ws;
    // workspace layout (bytes):
    //   xb    @ 0          : 8192*2048*2  = 33554432
    //   wqkvb @ 33554432   : 6144*2048*2  = 25165824
    //   woutb @ 58720256   : 2048*2048*2  =  8388608
    //   qkvb  @ 67108864   : 8192*6144*2  = 100663296   (end 167772160)
    //   attnb aliases xb (x no longer needed after GEMM1)
    u16* xb    = (u16*)(ws);
    u16* wqkvb = (u16*)(ws + 33554432);
    u16* woutb = (u16*)(ws + 58720256);
    u16* qkvb  = (u16*)(ws + 67108864);
    u16* attnb = xb;

    cvt_bf16<<<16384, 256, 0, stream>>>(x,     xb,    16777216 / 4);
    cvt_bf16<<<12288, 256, 0, stream>>>(w_qkv, wqkvb, 12582912 / 4);
    cvt_bf16<<<4096,  256, 0, stream>>>(w_out, woutb, 4194304 / 4);

    dim3 g1(24, 64);  // N/256, M/128
    gemm_nt<1><<<g1, 512, 0, stream>>>(xb, wqkvb, b_qkv, qkvb, 8192, 6144, 2048);

    attn<<<8192, 256, 0, stream>>>(qkvb, attnb);

    dim3 g2(8, 64);   // N/256, M/128
    gemm_nt<0><<<g2, 512, 0, stream>>>(attnb, woutb, b_out, out, 8192, 2048, 2048);
}